// Round 1
// baseline (196.070 us; speedup 1.0000x reference)
//
#include <hip/hip_runtime.h>

// out[n,h] = sum_{i<48,j<48} obs_re[h,i,j] * x[n,i] * x[n,j]
// (imaginary part cancels: psi is real; padding beyond 48 is zero)

#define N_TOKENS 65536   // B*T = 16*4096
#define C 48             // n_embed
#define ODIM 64          // observable dim (we only touch 48x48 block)
#define NHEAD 8

__global__ __launch_bounds__(256) void qform_fp32_kernel(
    const float* __restrict__ x,        // (N_TOKENS, 48)
    const float* __restrict__ obs_re,   // (8, 64, 64)
    float* __restrict__ out)            // (N_TOKENS, 8)
{
    const int t = blockIdx.x * 256 + threadIdx.x;  // one token per thread

    // Load x[t][0..47] into registers via 12 float4 (t*48*4 = t*192 bytes, 16B aligned)
    const float4* xg = (const float4*)(x + (size_t)t * C);
    float xs[C];
    #pragma unroll
    for (int q = 0; q < 12; ++q) {
        float4 v = xg[q];
        xs[4*q+0] = v.x; xs[4*q+1] = v.y; xs[4*q+2] = v.z; xs[4*q+3] = v.w;
    }

    float acc[NHEAD];
    #pragma unroll
    for (int h = 0; h < NHEAD; ++h) acc[h] = 0.f;

    // i-loop NOT unrolled (keeps I-cache small); h and j loops fully unrolled.
    for (int i = 0; i < C; ++i) {
        const float xi = x[(size_t)t * C + i];   // L1-resident reload (runtime i
                                                 // can't index the register array)
        #pragma unroll
        for (int h = 0; h < NHEAD; ++h) {
            // Uniform (lane-invariant) address -> compiler should emit s_load_dwordx4
            const float4* Mrow = (const float4*)(obs_re + ((size_t)(h * ODIM + i) * ODIM));
            float s0 = 0.f, s1 = 0.f, s2 = 0.f, s3 = 0.f;
            #pragma unroll
            for (int q = 0; q < 12; ++q) {       // j = 0..47
                float4 m = Mrow[q];
                s0 += m.x * xs[4*q+0];
                s1 += m.y * xs[4*q+1];
                s2 += m.z * xs[4*q+2];
                s3 += m.w * xs[4*q+3];
            }
            acc[h] += xi * ((s0 + s1) + (s2 + s3));
        }
    }

    // out[t][0..7], two float4 stores
    float4* o4 = (float4*)(out + (size_t)t * NHEAD);
    o4[0] = make_float4(acc[0], acc[1], acc[2], acc[3]);
    o4[1] = make_float4(acc[4], acc[5], acc[6], acc[7]);
}

extern "C" void kernel_launch(void* const* d_in, const int* in_sizes, int n_in,
                              void* d_out, int out_size, void* d_ws, size_t ws_size,
                              hipStream_t stream) {
    const float* x      = (const float*)d_in[0];  // (16,4096,48) fp32
    const float* obs_re = (const float*)d_in[1];  // (8,64,64) fp32
    // d_in[2] = obs_im: mathematically unused (Re(psi^H O psi) with real psi)
    float* out = (float*)d_out;                   // (16,4096,8) fp32

    qform_fp32_kernel<<<N_TOKENS / 256, 256, 0, stream>>>(x, obs_re, out);
}

// Round 2
// 71.981 us; speedup vs baseline: 2.7239x; 2.7239x over previous
//
#include <hip/hip_runtime.h>

// exp[n,h] = sum_{i<48,j<48} obs_re[h,i,j] * x[n,i] * x[n,j]
// (psi real => imaginary part cancels; obs_im unused; padding j,i>=48 is zero)
//
// MFMA formulation per head h, per 16-token group:
//   D[i'][tok'] = sum_j O[h, i, j] * x[tok, j]   (mfma_f32_16x16x32_bf16)
//   A = O_h tile   (M=i, K=j)  -- pre-swizzled to frag order by prep kernel
//   B = x^T tile   (K=j, N=tok) -- from LDS, j>=48 zeroed
//   exp[tok,h] = sum_i x[tok,i] * D[i][tok]  -- 12 in-thread FMA + 2 shfl_xor

#define NTOK 65536
#define CDIM 48
#define ODIM 64
#define NHEAD 8
#define XSTRIDE 56   // bf16 elems per LDS row (48 data + 8 pad) = 112 B

typedef __attribute__((ext_vector_type(8))) short short8;
typedef __attribute__((ext_vector_type(4))) short short4v;
typedef __attribute__((ext_vector_type(4))) float float4v;

static __device__ __forceinline__ short f2bf(float f) {
    unsigned int u = __builtin_bit_cast(unsigned int, f);
    u += 0x7FFFu + ((u >> 16) & 1u);            // round-to-nearest-even
    return (short)(u >> 16);
}
static __device__ __forceinline__ float bf2f(short s) {
    return __builtin_bit_cast(float, ((unsigned int)(unsigned short)s) << 16);
}

// ---- prep: obs_re (8,64,64) fp32 -> bf16 A-frags in ws ----
// frag f = h*6 + kt*3 + it; lane (q=lane>>4, c=lane&15) holds
// A[m=c][k=8q+jj] with i = 16*it + c, j = 32*kt + 8q + jj  (jj=0..7)
__global__ __launch_bounds__(256) void prep_obs(const float* __restrict__ obs,
                                                short* __restrict__ ws) {
    int g = blockIdx.x * 256 + threadIdx.x;      // 0..3071
    int f = g >> 6, lane = g & 63;
    int h = f / 6, rem = f % 6, kt = rem / 3, it = rem % 3;
    int q = lane >> 4, c = lane & 15;
    int i = 16 * it + c;
    int j0 = 32 * kt + 8 * q;
    const float* src = obs + ((size_t)(h * ODIM + i) * ODIM + j0);
    short8 v;
    #pragma unroll
    for (int jj = 0; jj < 8; ++jj) v[jj] = f2bf(src[jj]);
    *(short8*)(ws + ((size_t)f * 64 + lane) * 8) = v;
}

// ---- main kernel ----
static __device__ __forceinline__ void head_compute(
    const short8 A[6], const short8 bfr[2], const float xe[3][4],
    float* __restrict__ out, int obase, int h, int lane)
{
    float4v acc[3];
    #pragma unroll
    for (int it = 0; it < 3; ++it) {
        float4v z = {0.f, 0.f, 0.f, 0.f};
        acc[it] = __builtin_amdgcn_mfma_f32_16x16x32_bf16(A[it],     bfr[0], z,       0, 0, 0);
        acc[it] = __builtin_amdgcn_mfma_f32_16x16x32_bf16(A[3 + it], bfr[1], acc[it], 0, 0, 0);
    }
    float p = 0.f;
    #pragma unroll
    for (int it = 0; it < 3; ++it)
        #pragma unroll
        for (int r = 0; r < 4; ++r)
            p += acc[it][r] * xe[it][r];
    p += __shfl_xor(p, 16, 64);   // reduce across quads (i mod 16 groups)
    p += __shfl_xor(p, 32, 64);
    if (lane < 16) out[obase + h] = p;   // q==0 lanes: one token each
}

__global__ __launch_bounds__(256) void qform_mfma(const float* __restrict__ x,
                                                  const short* __restrict__ ws,
                                                  float* __restrict__ out) {
    __shared__ short xl[64 * XSTRIDE];
    const int tid = threadIdx.x;
    const int tb = blockIdx.x * 64;              // 64 tokens per block

    // stage x (64 tokens x 48 fp32) -> LDS bf16, coalesced float4 reads
    #pragma unroll
    for (int s = 0; s < 3; ++s) {
        int idx = s * 256 + tid;                 // 0..767 float4 chunks
        int t = idx / 12, ch = idx % 12;         // 12 float4 per token row
        float4 v = ((const float4*)x)[(size_t)tb * 12 + idx];
        short4v b;
        b.x = f2bf(v.x); b.y = f2bf(v.y); b.z = f2bf(v.z); b.w = f2bf(v.w);
        *(short4v*)(xl + t * XSTRIDE + ch * 4) = b;
    }
    __syncthreads();

    const int w = tid >> 6, lane = tid & 63;
    const int q = lane >> 4, c = lane & 15;
    const int row = w * 16 + c;                  // token index within block

    // B frags: lane holds B[k=8q+jj][n=c] = x[row][8q+jj (+32)]
    short8 bfr[2];
    bfr[0] = *(const short8*)(xl + row * XSTRIDE + q * 8);
    if (q < 2)
        bfr[1] = *(const short8*)(xl + row * XSTRIDE + q * 8 + 32);
    else
        bfr[1] = (short8)0;                      // j >= 48: xpad = 0

    // epilogue x values: x[row][i = 16it + 4q + r], head-independent
    float xe[3][4];
    #pragma unroll
    for (int it = 0; it < 3; ++it)
        #pragma unroll
        for (int r = 0; r < 4; ++r)
            xe[it][r] = bf2f(xl[row * XSTRIDE + 16 * it + 4 * q + r]);

    const short8* aw = (const short8*)ws;        // frag f at aw[f*64 + lane]
    const int obase = (tb + w * 16 + c) * NHEAD;

    // head loop, A-frags double-buffered (6 frags = 24 VGPR each buffer)
    short8 A0[6], A1[6];
    #pragma unroll
    for (int u = 0; u < 6; ++u) A0[u] = aw[u * 64 + lane];

    for (int h = 0; h < 8; h += 2) {
        #pragma unroll
        for (int u = 0; u < 6; ++u) A1[u] = aw[((h + 1) * 6 + u) * 64 + lane];
        head_compute(A0, bfr, xe, out, obase, h, lane);
        #pragma unroll
        for (int u = 0; u < 6; ++u) A0[u] = aw[(((h + 2) & 7) * 6 + u) * 64 + lane];
        head_compute(A1, bfr, xe, out, obase, h + 1, lane);
    }
}

extern "C" void kernel_launch(void* const* d_in, const int* in_sizes, int n_in,
                              void* d_out, int out_size, void* d_ws, size_t ws_size,
                              hipStream_t stream) {
    const float* x      = (const float*)d_in[0];   // (16,4096,48)
    const float* obs_re = (const float*)d_in[1];   // (8,64,64)
    // d_in[2] = obs_im: unused (Re(psi^H O psi) with real psi)
    float* out = (float*)d_out;                    // (16,4096,8)
    short* ws  = (short*)d_ws;                     // 48 KB of A-frags

    prep_obs<<<12, 256, 0, stream>>>(obs_re, ws);
    qform_mfma<<<NTOK / 64, 256, 0, stream>>>(x, ws, out);
}

// Round 3
// 71.866 us; speedup vs baseline: 2.7283x; 1.0016x over previous
//
#include <hip/hip_runtime.h>

// exp[n,h] = sum_{i<48,j<48} obs_re[h,i,j] * x[n,i] * x[n,j]
// (psi real => Im part cancels; obs_im unused; padding i,j>=48 zero)
//
// Single fused kernel. Per block: stage obs_re -> bf16 MFMA A-fragments in
// LDS (48 KB, done once, reused by all waves/groups) + 128-token x tile in
// LDS (bf16, row stride 112 B). Per wave: 2 token-groups x 8 heads via
// mfma_f32_16x16x32_bf16; epilogue dot + 2x shfl_xor; coalesced float4 out.

#define NTOK 65536
#define NHEAD 8
#define XSTRIDE 56           // shorts per LDS x-row (48 data + 8 pad) = 112 B (7*16: b128-aligned)
#define TPB 128              // tokens per block (4 waves x 2 groups x 16)

typedef __attribute__((ext_vector_type(8))) short short8;
typedef __attribute__((ext_vector_type(4))) short short4v;
typedef __attribute__((ext_vector_type(4))) float float4v;

static __device__ __forceinline__ short f2bf(float f) {
    unsigned int u = __builtin_bit_cast(unsigned int, f);
    u += 0x7FFFu + ((u >> 16) & 1u);        // round-to-nearest-even
    return (short)(u >> 16);
}
static __device__ __forceinline__ float bf2f(short s) {
    return __builtin_bit_cast(float, ((unsigned int)(unsigned short)s) << 16);
}

__global__ __launch_bounds__(256, 2) void qform_fused(
    const float* __restrict__ x,        // (65536, 48)
    const float* __restrict__ obs,      // (8, 64, 64)
    float* __restrict__ out)            // (65536, 8)
{
    __shared__ short a_lds[48 * 64 * 8];        // 48 frags x 64 lanes x 16 B = 48 KB
    __shared__ short xl[TPB * XSTRIDE];         // 14 KB

    const int tid  = threadIdx.x;
    const int w    = tid >> 6, lane = tid & 63;
    const int q    = lane >> 4, c = lane & 15;
    const int tb   = blockIdx.x * TPB;

    // ---- stage A-frags: frag f = h*6 + kt*3 + it; lane (q,c) holds
    // A[m=c][k=8q+jj] = obs[h][16it+c][32kt+8q+jj]  (validated in round 2) ----
    #pragma unroll
    for (int u = 0; u < 12; ++u) {
        int f = u * 4 + w;                      // wave w stages frags w, w+4, ...
        int h = f / 6, rem = f % 6, kt = rem / 3, it = rem % 3;
        const float4* src = (const float4*)(obs +
            ((size_t)(h * 64 + 16 * it + c) * 64 + 32 * kt + 8 * q));
        float4 v0 = src[0], v1 = src[1];
        short8 a;
        a[0] = f2bf(v0.x); a[1] = f2bf(v0.y); a[2] = f2bf(v0.z); a[3] = f2bf(v0.w);
        a[4] = f2bf(v1.x); a[5] = f2bf(v1.y); a[6] = f2bf(v1.z); a[7] = f2bf(v1.w);
        *(short8*)(a_lds + ((size_t)f * 64 + lane) * 8) = a;
    }

    // ---- stage x tile: 128 tokens x 12 float4, coalesced ----
    #pragma unroll
    for (int s = 0; s < 6; ++s) {
        int idx = s * 256 + tid;                // 0..1535
        int t = idx / 12, ch = idx % 12;
        float4 v = ((const float4*)x)[(size_t)tb * 12 + idx];
        short4v b;
        b.x = f2bf(v.x); b.y = f2bf(v.y); b.z = f2bf(v.z); b.w = f2bf(v.w);
        *(short4v*)(xl + t * XSTRIDE + ch * 4) = b;
    }
    __syncthreads();

    // ---- per-wave compute: 2 groups of 16 tokens ----
    short8 bfr[2][2];
    float  xe[2][3][4];
    #pragma unroll
    for (int g = 0; g < 2; ++g) {
        const int row = w * 32 + g * 16 + c;    // token within block
        bfr[g][0] = *(const short8*)(xl + row * XSTRIDE + q * 8);
        if (q < 2)
            bfr[g][1] = *(const short8*)(xl + row * XSTRIDE + 32 + q * 8);
        else
            bfr[g][1] = (short8)0;              // j >= 48: psi-pad is zero
        #pragma unroll
        for (int it = 0; it < 3; ++it)
            #pragma unroll
            for (int r = 0; r < 4; ++r)
                xe[g][it][r] = bf2f(xl[row * XSTRIDE + 16 * it + 4 * q + r]);
    }

    float ph[2][NHEAD];                         // per-group, all-head results
    #pragma unroll
    for (int h = 0; h < NHEAD; ++h) {
        short8 A[6];
        #pragma unroll
        for (int u = 0; u < 6; ++u)
            A[u] = *(const short8*)(a_lds + ((size_t)(h * 6 + u) * 64 + lane) * 8);
        #pragma unroll
        for (int g = 0; g < 2; ++g) {
            float4v acc[3];
            #pragma unroll
            for (int it = 0; it < 3; ++it) {
                float4v z = {0.f, 0.f, 0.f, 0.f};
                acc[it] = __builtin_amdgcn_mfma_f32_16x16x32_bf16(A[it],     bfr[g][0], z,       0, 0, 0);
                acc[it] = __builtin_amdgcn_mfma_f32_16x16x32_bf16(A[3 + it], bfr[g][1], acc[it], 0, 0, 0);
            }
            float p = 0.f;
            #pragma unroll
            for (int it = 0; it < 3; ++it)
                #pragma unroll
                for (int r = 0; r < 4; ++r)
                    p += acc[it][r] * xe[g][it][r];   // x[row][16it+4q+r] * D[i][row]
            p += __shfl_xor(p, 16, 64);               // reduce over q (i mod-16 groups)
            p += __shfl_xor(p, 32, 64);
            ph[g][h] = p;
        }
    }

    // ---- coalesced store: lanes 0..15 each own one token per group ----
    if (lane < 16) {
        #pragma unroll
        for (int g = 0; g < 2; ++g) {
            float4* o4 = (float4*)(out + (size_t)(tb + w * 32 + g * 16 + c) * NHEAD);
            o4[0] = make_float4(ph[g][0], ph[g][1], ph[g][2], ph[g][3]);
            o4[1] = make_float4(ph[g][4], ph[g][5], ph[g][6], ph[g][7]);
        }
    }
}

extern "C" void kernel_launch(void* const* d_in, const int* in_sizes, int n_in,
                              void* d_out, int out_size, void* d_ws, size_t ws_size,
                              hipStream_t stream) {
    const float* x      = (const float*)d_in[0];   // (16,4096,48)
    const float* obs_re = (const float*)d_in[1];   // (8,64,64)
    // d_in[2] = obs_im: unused (Re(psi^H O psi) with real psi)
    float* out = (float*)d_out;                    // (16,4096,8)

    qform_fused<<<NTOK / TPB, 256, 0, stream>>>(x, obs_re, out);
}